// Round 1
// baseline (1377.699 us; speedup 1.0000x reference)
//
#include <hip/hip_runtime.h>
#include <hip/hip_bf16.h>
#include <math.h>

#define DEV __device__ __forceinline__

// ---------------- problem constants ----------------
constexpr int N_CONST = 8192;
constexpr int E_CONST = 131072;

constexpr float SQ3F     = 1.7320508075688772f;
constexpr float INV_SQ3F = 0.57735026918962576f;
constexpr float FAN_TP   = 0.20412414523193150f;   // 24^-0.5
constexpr float FAN_TP_V = 0.35355339059327373f;   // sqrt(3)*24^-0.5
constexpr float FAN_DOT  = 0.11180339887498949f;   // 80^-0.5
constexpr float INV16SQ  = 0.25f;                  // 16^-0.5
constexpr float INV8SQ   = 0.35355339059327373f;   // 8^-0.5
constexpr float HID_SC   = 0.125f;                 // 64^-0.5

// ---------------- workspace layout (float offsets) ----------------
enum : int {
  OFF_LIN0 = 0,
  OFF_LIN1 = OFF_LIN0 + 256,
  OFF_HQ0  = OFF_LIN1 + 64,
  OFF_HQ1  = OFF_HQ0 + 256,
  OFF_FCK1 = OFF_HQ1 + 64,
  OFF_FCK2 = OFF_FCK1 + 2048,
  OFF_FCV1 = OFF_FCK2 + 36864,
  OFF_FCV2 = OFF_FCV1 + 2048,
  OFF_DOT0 = OFF_FCV2 + 73728,
  OFF_DOT1 = OFF_DOT0 + 128,
  OFF_RB0  = OFF_DOT1 + 32,
  OFF_RB1  = OFF_RB0 + 128,
  OFF_RE0  = OFF_RB1 + 32,
  OFF_RE1  = OFF_RE0 + 128,
  OFF_F    = OFF_RE1 + 32,
  OFF_POS  = OFF_F + N_CONST * 40,
  OFF_X    = OFF_POS + N_CONST * 3,
  OFF_Q    = OFF_X + N_CONST * 40,
  OFF_MX   = OFF_Q + N_CONST * 20,
  OFF_Z    = OFF_MX + N_CONST,
  OFF_AGG  = OFF_Z + N_CONST,
  OFF_LOGIT= OFF_AGG + N_CONST * 40,
  OFF_CUT  = OFF_LOGIT + E_CONST,
  OFF_EX   = OFF_CUT + E_CONST,
  OFF_FLAG = OFF_EX + E_CONST,   // int flag stored in a float slot
};

// ---------------- dtype detection ----------------
// bf16 data: bits 8..14 of each 32-bit word are the (sign-stripped) top of a
// bf16 exponent -> concentrated near 0x3D..0x41 for ~N(0,1) data.
// f32 data: bits 8..14 are mantissa bits -> uniform. Count hits over 512 words.
__global__ void k_detect(const unsigned int* __restrict__ words, int* __restrict__ flag) {
  if (blockIdx.x != 0 || threadIdx.x != 0) return;
  int cnt = 0;
  for (int i = 0; i < 512; ++i) {
    unsigned b = (words[i] >> 8) & 0x7Fu;
    cnt += (b >= 0x3Au && b <= 0x43u) ? 1 : 0;
  }
  *flag = (cnt > 256) ? 1 : 0;
}

// ---------------- convert all float inputs to f32 in ws ----------------
struct CvtArgs {
  const void* src[16];
  int n[16];
  int off[16];
};

template <bool BF>
__global__ void k_cvt(CvtArgs a, float* __restrict__ ws, const int* __restrict__ flag) {
  if ((*flag != 0) != BF) return;
  int tid = blockIdx.x * blockDim.x + threadIdx.x;
  int stride = gridDim.x * blockDim.x;
  for (int arr = 0; arr < 16; ++arr) {
    float* dst = ws + a.off[arr];
    int n = a.n[arr];
    if (BF) {
      const __hip_bfloat16* s = (const __hip_bfloat16*)a.src[arr];
      for (int i = tid; i < n; i += stride) dst[i] = __bfloat162float(s[i]);
    } else {
      const float* s = (const float*)a.src[arr];
      for (int i = tid; i < n; i += stride) dst[i] = s[i];
    }
  }
}

// ---------------- helpers ----------------
DEV void atomicMaxF(float* addr, float val) {
  unsigned int* ai = (unsigned int*)addr;
  unsigned int old = *ai;
  while (__uint_as_float(old) < val) {
    unsigned int assumed = old;
    old = atomicCAS(ai, assumed, __float_as_uint(val));
    if (old == assumed) break;
  }
}

// e3nn o3.Linear on 16x0e+8x1o input -> MO0 x0e + MO1 x1o
template <int MO0, int MO1>
DEV void lin_apply(const float* __restrict__ in40, const float* __restrict__ W0,
                   const float* __restrict__ W1, float* __restrict__ out) {
#pragma unroll
  for (int j = 0; j < MO0; ++j) {
    float a = 0.f;
#pragma unroll
    for (int i = 0; i < 16; ++i) a += in40[i] * W0[i * MO0 + j];
    out[j] = a * INV16SQ;
  }
#pragma unroll
  for (int w = 0; w < MO1; ++w) {
    float a0 = 0.f, a1 = 0.f, a2 = 0.f;
#pragma unroll
    for (int u = 0; u < 8; ++u) {
      float wt = W1[u * MO1 + w];
      a0 += in40[16 + u * 3 + 0] * wt;
      a1 += in40[16 + u * 3 + 1] * wt;
      a2 += in40[16 + u * 3 + 2] * wt;
    }
    out[MO0 + w * 3 + 0] = a0 * INV8SQ;
    out[MO0 + w * 3 + 1] = a1 * INV8SQ;
    out[MO0 + w * 3 + 2] = a2 * INV8SQ;
  }
}

DEV void edge_emb(float d, float emb[16]) {
#pragma unroll
  for (int i = 0; i < 16; ++i) {
    float c = (2.0f * (i + 1)) / 17.0f;
    float df = (d - c) * (17.0f * 0.5f);
    emb[i] = __expf(-df * df) * (4.0f / 1.12f);
  }
}

DEV void radial_hidden(const float* __restrict__ W1, const float emb[16], float h[64]) {
#pragma unroll 1
  for (int k = 0; k < 64; ++k) {
    float a = 0.f;
#pragma unroll
    for (int i = 0; i < 16; ++i) a += emb[i] * W1[i * 64 + k];
    a *= INV16SQ;  // NB^-0.5, NB=16
    float sig = 1.0f / (1.0f + __expf(-a));
    h[k] = a * sig * HID_SC;  // fold 64^-0.5 into h
  }
}

// ---------------- node kernels ----------------
__global__ void k_lin_in(const float* __restrict__ f, const float* __restrict__ W0,
                         const float* __restrict__ W1, float* __restrict__ x, int N) {
  int n = blockIdx.x * blockDim.x + threadIdx.x;
  if (n >= N) return;
  lin_apply<16, 8>(f + n * 40, W0, W1, x + n * 40);
}

__global__ void k_q(const float* __restrict__ x, const float* __restrict__ W0,
                    const float* __restrict__ W1, float* __restrict__ q, int N) {
  int n = blockIdx.x * blockDim.x + threadIdx.x;
  if (n >= N) return;
  lin_apply<8, 4>(x + n * 40, W0, W1, q + n * 20);
}

__global__ void k_init(float* __restrict__ mx, float* __restrict__ z,
                       float* __restrict__ agg, int N) {
  int i = blockIdx.x * blockDim.x + threadIdx.x;
  if (i < N * 40) agg[i] = 0.f;
  if (i < N) { mx[i] = -INFINITY; z[i] = 0.f; }
}

__global__ void k_update(float* __restrict__ x, const float* __restrict__ agg, int n) {
  int i = blockIdx.x * blockDim.x + threadIdx.x;
  if (i < n) x[i] += agg[i];
}

// ---------------- edge kernel 1: K path + logits ----------------
__global__ void k_edge_k(const float* __restrict__ pos, const float* __restrict__ x,
                         const float* __restrict__ q,
                         const float* __restrict__ fck1, const float* __restrict__ fck2,
                         const float* __restrict__ dot0, const float* __restrict__ dot1,
                         const int* __restrict__ srcv, const int* __restrict__ dstv,
                         float* __restrict__ logit, float* __restrict__ cutb,
                         float* __restrict__ mx, int E) {
  int e = blockIdx.x * blockDim.x + threadIdx.x;
  if (e >= E) return;
  int s = srcv[e], t = dstv[e];

  float y1[3], d;
  {
    float vx = pos[s * 3 + 0] - pos[t * 3 + 0];
    float vy = pos[s * 3 + 1] - pos[t * 3 + 1];
    float vz = pos[s * 3 + 2] - pos[t * 3 + 2];
    d = sqrtf(vx * vx + vy * vy + vz * vz + 1e-24f);
    float inv = SQ3F / d;
    y1[0] = vx * inv; y1[1] = vy * inv; y1[2] = vz * inv;
  }
  float emb[16];
  edge_emb(d, emb);
  float uu = 10.0f * (1.0f - 0.5f * d);
  float cut = (uu > 0.f) ? __expf(-1.0f / fmaxf(uu, 1e-9f)) : 0.f;

  const float* xs = x + s * 40;
  float fs[16];
#pragma unroll
  for (int i = 0; i < 16; ++i) fs[i] = xs[i];
  float fv[8][3];
#pragma unroll
  for (int u = 0; u < 8; ++u) {
    fv[u][0] = xs[16 + u * 3 + 0];
    fv[u][1] = xs[16 + u * 3 + 1];
    fv[u][2] = xs[16 + u * 3 + 2];
  }
  float vy[8];
#pragma unroll
  for (int u = 0; u < 8; ++u)
    vy[u] = (fv[u][0] * y1[0] + fv[u][1] * y1[1] + fv[u][2] * y1[2]) * INV_SQ3F;

  float h[64];
  radial_hidden(fck1, emb, h);

  float ks[8] = {0}, a2[4] = {0}, a3[4][3] = {{0}};
#pragma unroll 1
  for (int k = 0; k < 64; ++k) {
    float hk = h[k];
    const float* r = fck2 + k * 288;
#pragma unroll
    for (int u = 0; u < 16; ++u) {           // W1: 0e x 0e -> 0e
      float fu = hk * fs[u];
#pragma unroll
      for (int w = 0; w < 8; ++w) ks[w] += fu * r[u * 8 + w];
    }
#pragma unroll
    for (int u = 0; u < 16; ++u) {           // W2: 0e x 1o -> 1o (y1 separable)
      float fu = hk * fs[u];
#pragma unroll
      for (int w = 0; w < 4; ++w) a2[w] += fu * r[128 + u * 4 + w];
    }
#pragma unroll
    for (int u = 0; u < 8; ++u) {            // W3: 1o x 0e -> 1o
      float c0 = hk * fv[u][0], c1 = hk * fv[u][1], c2 = hk * fv[u][2];
#pragma unroll
      for (int w = 0; w < 4; ++w) {
        float wt = r[192 + u * 4 + w];
        a3[w][0] += c0 * wt; a3[w][1] += c1 * wt; a3[w][2] += c2 * wt;
      }
    }
#pragma unroll
    for (int u = 0; u < 8; ++u) {            // W4: 1o x 1o -> 0e
      float vu = hk * vy[u];
#pragma unroll
      for (int w = 0; w < 8; ++w) ks[w] += vu * r[224 + u * 8 + w];
    }
  }

  // finalize K fragments
  float kvf[4][3];
#pragma unroll
  for (int v = 0; v < 4; ++v) {
#pragma unroll
    for (int i = 0; i < 3; ++i)
      kvf[v][i] = a2[v] * y1[i] * FAN_TP + a3[v][i] * FAN_TP_V;
  }

  const float* qd = q + t * 20;
  float lg = 0.f;
#pragma unroll
  for (int u = 0; u < 8; ++u) {
    float qu = qd[u] * FAN_TP;
#pragma unroll
    for (int v = 0; v < 8; ++v) lg += qu * ks[v] * dot0[u * 8 + v];
  }
#pragma unroll
  for (int u = 0; u < 4; ++u) {
    float q0 = qd[8 + u * 3 + 0], q1 = qd[8 + u * 3 + 1], q2 = qd[8 + u * 3 + 2];
#pragma unroll
    for (int v = 0; v < 4; ++v) {
      float wt = dot1[u * 4 + v] * INV_SQ3F;
      lg += (q0 * kvf[v][0] + q1 * kvf[v][1] + q2 * kvf[v][2]) * wt;
    }
  }
  lg *= FAN_DOT;

  logit[e] = lg;
  cutb[e] = cut;
  atomicMaxF(&mx[t], lg);
}

// ---------------- edge kernel 2: exp + denominator ----------------
__global__ void k_edge_ex(const int* __restrict__ dstv, const float* __restrict__ logit,
                          const float* __restrict__ cutb, const float* __restrict__ mx,
                          float* __restrict__ ex, float* __restrict__ z, int E) {
  int e = blockIdx.x * blockDim.x + threadIdx.x;
  if (e >= E) return;
  int t = dstv[e];
  float m = mx[t];
  if (m == -INFINITY) m = 0.f;
  float v = cutb[e] * __expf(logit[e] - m);
  ex[e] = v;
  atomicAdd(&z[t], v);
}

// ---------------- edge kernel 3: V path + scatter ----------------
__global__ void k_edge_v(const float* __restrict__ pos, const float* __restrict__ x,
                         const float* __restrict__ fcv1, const float* __restrict__ fcv2,
                         const int* __restrict__ srcv, const int* __restrict__ dstv,
                         const float* __restrict__ ex, const float* __restrict__ z,
                         float* __restrict__ agg, int E) {
  int e = blockIdx.x * blockDim.x + threadIdx.x;
  if (e >= E) return;
  int s = srcv[e], t = dstv[e];

  float y1[3], d;
  {
    float vx = pos[s * 3 + 0] - pos[t * 3 + 0];
    float vy = pos[s * 3 + 1] - pos[t * 3 + 1];
    float vz = pos[s * 3 + 2] - pos[t * 3 + 2];
    d = sqrtf(vx * vx + vy * vy + vz * vz + 1e-24f);
    float inv = SQ3F / d;
    y1[0] = vx * inv; y1[1] = vy * inv; y1[2] = vz * inv;
  }
  float emb[16];
  edge_emb(d, emb);

  const float* xs = x + s * 40;
  float fs[16];
#pragma unroll
  for (int i = 0; i < 16; ++i) fs[i] = xs[i];
  float fv[8][3];
#pragma unroll
  for (int u = 0; u < 8; ++u) {
    fv[u][0] = xs[16 + u * 3 + 0];
    fv[u][1] = xs[16 + u * 3 + 1];
    fv[u][2] = xs[16 + u * 3 + 2];
  }
  float vy[8];
#pragma unroll
  for (int u = 0; u < 8; ++u)
    vy[u] = (fv[u][0] * y1[0] + fv[u][1] * y1[1] + fv[u][2] * y1[2]) * INV_SQ3F;

  float h[64];
  radial_hidden(fcv1, emb, h);

  float vs[16] = {0}, b2[8] = {0}, b3[8][3] = {{0}};
#pragma unroll 1
  for (int k = 0; k < 64; ++k) {
    float hk = h[k];
    const float* r = fcv2 + k * 576;
#pragma unroll
    for (int u = 0; u < 16; ++u) {           // W1: 16x16
      float fu = hk * fs[u];
#pragma unroll
      for (int w = 0; w < 16; ++w) vs[w] += fu * r[u * 16 + w];
    }
#pragma unroll
    for (int u = 0; u < 16; ++u) {           // W2: 16x8
      float fu = hk * fs[u];
#pragma unroll
      for (int w = 0; w < 8; ++w) b2[w] += fu * r[256 + u * 8 + w];
    }
#pragma unroll
    for (int u = 0; u < 8; ++u) {            // W3: 8x8
      float c0 = hk * fv[u][0], c1 = hk * fv[u][1], c2 = hk * fv[u][2];
#pragma unroll
      for (int w = 0; w < 8; ++w) {
        float wt = r[384 + u * 8 + w];
        b3[w][0] += c0 * wt; b3[w][1] += c1 * wt; b3[w][2] += c2 * wt;
      }
    }
#pragma unroll
    for (int u = 0; u < 8; ++u) {            // W4: 8x16
      float vu = hk * vy[u];
#pragma unroll
      for (int w = 0; w < 16; ++w) vs[w] += vu * r[448 + u * 16 + w];
    }
  }

  float zz = z[t];
  zz = (zz == 0.f) ? 1.f : zz;
  float alpha = ex[e] / zz;
  float wgt = sqrtf(alpha + 1e-12f);

  float* at = agg + t * 40;
#pragma unroll
  for (int w = 0; w < 16; ++w) atomicAdd(&at[w], wgt * vs[w] * FAN_TP);
#pragma unroll
  for (int w = 0; w < 8; ++w) {
#pragma unroll
    for (int i = 0; i < 3; ++i) {
      float v = b2[w] * y1[i] * FAN_TP + b3[w][i] * FAN_TP_V;
      atomicAdd(&at[16 + w * 3 + i], wgt * v);
    }
  }
}

// ---------------- output kernel ----------------
template <bool BF>
__global__ void k_out(const float* __restrict__ x, const float* __restrict__ rb0,
                      const float* __restrict__ rb1, const float* __restrict__ re0,
                      const float* __restrict__ re1, void* __restrict__ out, int N,
                      const int* __restrict__ flag) {
  if ((*flag != 0) != BF) return;
  int n = blockIdx.x * blockDim.x + threadIdx.x;
  if (n >= N) return;
  float b[20], eta[20];
  lin_apply<8, 4>(x + n * 40, rb0, rb1, b);
  lin_apply<8, 4>(x + n * 40, re0, re1, eta);
  if (BF) {
    __hip_bfloat16* o = (__hip_bfloat16*)out;
#pragma unroll
    for (int j = 0; j < 20; ++j) o[n * 20 + j] = __float2bfloat16(b[j]);
#pragma unroll
    for (int j = 0; j < 20; ++j) o[N * 20 + n * 20 + j] = __float2bfloat16(eta[j]);
  } else {
    float* o = (float*)out;
#pragma unroll
    for (int j = 0; j < 20; ++j) o[n * 20 + j] = b[j];
#pragma unroll
    for (int j = 0; j < 20; ++j) o[N * 20 + n * 20 + j] = eta[j];
  }
}

// ---------------- host ----------------
extern "C" void kernel_launch(void* const* d_in, const int* in_sizes, int n_in,
                              void* d_out, int out_size, void* d_ws, size_t ws_size,
                              hipStream_t stream) {
  float* ws = (float*)d_ws;
  const int N = in_sizes[0] / 40;
  const int E = in_sizes[16];
  const int* src = (const int*)d_in[16];
  const int* dst = (const int*)d_in[17];
  int* flag = (int*)(ws + OFF_FLAG);

  k_detect<<<1, 64, 0, stream>>>((const unsigned int*)d_in[0], flag);

  CvtArgs ca;
  const int order[16] = {2, 3, 4, 5, 6, 7, 8, 9, 10, 11, 12, 13, 14, 15, 0, 1};
  const int offs[16] = {OFF_LIN0, OFF_LIN1, OFF_HQ0, OFF_HQ1, OFF_FCK1, OFF_FCK2,
                        OFF_FCV1, OFF_FCV2, OFF_DOT0, OFF_DOT1, OFF_RB0, OFF_RB1,
                        OFF_RE0, OFF_RE1, OFF_F, OFF_POS};
  for (int i = 0; i < 16; ++i) {
    ca.src[i] = d_in[order[i]];
    ca.n[i] = in_sizes[order[i]];
    ca.off[i] = offs[i];
  }
  k_cvt<false><<<512, 256, 0, stream>>>(ca, ws, flag);
  k_cvt<true><<<512, 256, 0, stream>>>(ca, ws, flag);

  float* x = ws + OFF_X;
  float* q = ws + OFF_Q;
  float* mx = ws + OFF_MX;
  float* z = ws + OFF_Z;
  float* agg = ws + OFF_AGG;
  float* logit = ws + OFF_LOGIT;
  float* cutb = ws + OFF_CUT;
  float* exb = ws + OFF_EX;
  const float* pos = ws + OFF_POS;

  const int nodeBlocks = (N + 255) / 256;
  const int vecBlocks = (N * 40 + 255) / 256;
  const int edgeBlocks = (E + 255) / 256;

  k_lin_in<<<nodeBlocks, 256, 0, stream>>>(ws + OFF_F, ws + OFF_LIN0, ws + OFF_LIN1, x, N);

  for (int l = 0; l < 2; ++l) {
    k_init<<<vecBlocks, 256, 0, stream>>>(mx, z, agg, N);
    k_q<<<nodeBlocks, 256, 0, stream>>>(x, ws + OFF_HQ0 + l * 128, ws + OFF_HQ1 + l * 32, q, N);
    k_edge_k<<<edgeBlocks, 256, 0, stream>>>(
        pos, x, q, ws + OFF_FCK1 + l * 1024, ws + OFF_FCK2 + l * 18432,
        ws + OFF_DOT0 + l * 64, ws + OFF_DOT1 + l * 16, src, dst, logit, cutb, mx, E);
    k_edge_ex<<<edgeBlocks, 256, 0, stream>>>(dst, logit, cutb, mx, exb, z, E);
    k_edge_v<<<edgeBlocks, 256, 0, stream>>>(
        pos, x, ws + OFF_FCV1 + l * 1024, ws + OFF_FCV2 + l * 36864, src, dst, exb, z, agg, E);
    k_update<<<vecBlocks, 256, 0, stream>>>(x, agg, N * 40);
  }

  k_out<false><<<nodeBlocks, 256, 0, stream>>>(x, ws + OFF_RB0, ws + OFF_RB1,
                                               ws + OFF_RE0, ws + OFF_RE1, d_out, N, flag);
  k_out<true><<<nodeBlocks, 256, 0, stream>>>(x, ws + OFF_RB0, ws + OFF_RB1,
                                              ws + OFF_RE0, ws + OFF_RE1, d_out, N, flag);
}